// Round 4
// baseline (2156.063 us; speedup 1.0000x reference)
//
#include <hip/hip_runtime.h>
#include <cstdint>
#include <cstddef>

// B=32, S=512, I=256, H=512, E=1024, NH=16, HD=64
// Structural collapse (verified): only attention head 15 at s in [496,512)
// reaches the FC head; backward LSTM needs only its first 16 steps; Wo/Wfc
// fold to w_eff; w_eff-contracted Wv folds to wv2.
// Round 4: LLC-resident sync. 64 WGs = 2 batch-groups(16 b) x 32 col-groups
// (16 cols). h moves through a 4-slot ring (reused -> LLC-hot) gated by
// fresh per-step flags: producer wave0 does sc1 data stores ->
// s_waitcnt vmcnt(0) -> flag store; consumers poll only their segment's
// flag pair (no s_sleep), then gather. No fences anywhere.

typedef _Float16 v8h __attribute__((ext_vector_type(8)));
typedef _Float16 v4h __attribute__((ext_vector_type(4)));
typedef float    v4f __attribute__((ext_vector_type(4)));
typedef unsigned long long u64;

#define AT_LD(p)     __hip_atomic_load((p), __ATOMIC_RELAXED, __HIP_MEMORY_SCOPE_AGENT)
#define AT_ST(p, v)  __hip_atomic_store((p), (v), __ATOMIC_RELAXED, __HIP_MEMORY_SCOPE_AGENT)

// ---- workspace layout (bytes) ----
static constexpr size_t OFF_CNT   = 0;        // u32: join counter, epi-done
static constexpr size_t OFF_LOGIT = 256;      // 32 f32
static constexpr size_t OFF_BEFF  = 512;      // 1 f32
static constexpr size_t OFF_WEFF  = 1024;     // 1024 f32
static constexpr size_t OFF_FLAGF = 8192;                         // [512][2][32] u32
static constexpr size_t OFF_FLAGB = OFF_FLAGF + 512ull*64*4;      // [16][2][32] u32
static constexpr size_t ZERO_BYTES= OFF_FLAGB + 16ull*64*4;       // 143360
static constexpr size_t OFF_RINGF = ZERO_BYTES;                   // [4][2][16][512] f16
static constexpr size_t OFF_RINGB = OFF_RINGF + 4ull*2*16*512*2;  // same
static constexpr size_t OFF_HIST  = OFF_RINGB + 4ull*2*16*512*2;  // [32][16][1024] f32
static constexpr size_t OFF_WHHF  = OFF_HIST + 32ull*16*1024*4;   // 2048x512 f16
static constexpr size_t OFF_WIHF  = OFF_WHHF + 2048ull*512*2;     // 2048x256 f16
static constexpr size_t OFF_WHHB  = OFF_WIHF + 2048ull*256*2;
static constexpr size_t OFF_WIHB  = OFF_WHHB + 2048ull*512*2;
static constexpr size_t OFF_WKT   = OFF_WIHB + 2048ull*256*2;     // 1024x1024 f16
static constexpr size_t OFF_WQT   = OFF_WKT + 1024ull*1024*2;     // 1024x64 f16
static constexpr size_t OFF_WV2   = OFF_WQT + 1024ull*64*2;       // 16*1024*16 f32
static constexpr size_t OFF_CV    = OFF_WV2 + 16ull*1024*16*4;    // 256 f32
// total ~12.1 MiB

static constexpr int PSTR = 776;                    // panel stride f16 (16B-aligned)
static constexpr int GSTR = 68;                     // gates stride f32
static constexpr int LDS_PANEL_B = 16*PSTR*2;       // 24832
static constexpr int LDS_GATES_B = 64*GSTR*4;       // 17408
static constexpr int DYN_LDS = 53504;               // covers LSTM + epilogue
static constexpr u64 FLAG_PAIR = 0x0000000100000001ull;

// -------------------- prep kernels --------------------

__global__ void k_convert(const float* __restrict__ whhf, const float* __restrict__ wihf,
                          const float* __restrict__ whhb, const float* __restrict__ wihb,
                          char* __restrict__ ws)
{
    _Float16* o1 = (_Float16*)(ws + OFF_WHHF);
    _Float16* o2 = (_Float16*)(ws + OFF_WIHF);
    _Float16* o3 = (_Float16*)(ws + OFF_WHHB);
    _Float16* o4 = (_Float16*)(ws + OFF_WIHB);
    const int stride = gridDim.x * blockDim.x;
    for (int i = blockIdx.x*blockDim.x + threadIdx.x; i < 2048*512; i += stride) {
        o1[i] = (_Float16)whhf[i];
        o3[i] = (_Float16)whhb[i];
    }
    for (int i = blockIdx.x*blockDim.x + threadIdx.x; i < 2048*256; i += stride) {
        o2[i] = (_Float16)wihf[i];
        o4[i] = (_Float16)wihb[i];
    }
}

__global__ void k_weff(const float* __restrict__ Wfc, const float* __restrict__ Wo,
                       const float* __restrict__ bo, const float* __restrict__ bfc,
                       char* __restrict__ ws)
{
    float* weff = (float*)(ws + OFF_WEFF);
    float* beff = (float*)(ws + OFF_BEFF);
    const int bid = blockIdx.x;                 // 64 blocks
    const int e2 = (bid & 3)*256 + threadIdx.x;
    const int slab = bid >> 2;                  // 16 slabs of 64 e
    float a = 0.f;
    for (int e = slab*64; e < slab*64 + 64; ++e)
        a += Wfc[e] * Wo[(size_t)e*1024 + e2];
    atomicAdd(weff + e2, a);
    if ((bid & 3) == 0 && threadIdx.x < 64) {
        const int e = slab*64 + threadIdx.x;
        float b = Wfc[e]*bo[e];
        if (bid == 0 && threadIdx.x == 0) b += bfc[0];
        atomicAdd(beff, b);
    }
}

__global__ void k_wv2(const float* __restrict__ Wv, const float* __restrict__ bv,
                      char* __restrict__ ws)
{
    const float* weff = (const float*)(ws + OFF_WEFF);
    float* wv2 = (float*)(ws + OFF_WV2);
    float* cv  = (float*)(ws + OFF_CV);
    const int bid = blockIdx.x;                 // 65 blocks
    if (bid < 64) {
        const int r = bid >> 2;
        const int e = (bid & 3)*256 + threadIdx.x;
        for (int kh = 0; kh < 16; ++kh) {
            float a = 0.f;
            for (int hd = 0; hd < 64; ++hd)
                a += weff[r*64 + hd] * Wv[((size_t)(kh*64 + hd))*1024 + e];
            wv2[((size_t)r*1024 + e)*16 + kh] = a;
        }
    } else {
        const int r2 = threadIdx.x >> 4, k2 = threadIdx.x & 15;
        float a = 0.f;
        for (int hd = 0; hd < 64; ++hd)
            a += weff[r2*64 + hd] * bv[k2*64 + hd];
        cv[threadIdx.x] = a;
    }
}

__global__ void k_tk(const float* __restrict__ Wk, char* __restrict__ ws)
{
    _Float16* WkT = (_Float16*)(ws + OFF_WKT);
    __shared__ float tile[32][33];
    const int jt = blockIdx.x & 31, et = blockIdx.x >> 5;   // 1024 blocks
    const int tx = threadIdx.x & 31, ty = threadIdx.x >> 5; // 32x8
    for (int i = 0; i < 4; ++i)
        tile[ty + 8*i][tx] = Wk[((size_t)(jt*32 + ty + 8*i))*1024 + et*32 + tx];
    __syncthreads();
    for (int i = 0; i < 4; ++i)
        WkT[((size_t)(et*32 + ty + 8*i))*1024 + jt*32 + tx] = (_Float16)tile[tx][ty + 8*i];
}

__global__ void k_tq(const float* __restrict__ Wq, char* __restrict__ ws)
{
    _Float16* WqT = (_Float16*)(ws + OFF_WQT);
    const int gid = blockIdx.x*256 + threadIdx.x;  // 256 blocks
    const int d = gid & 63, e = gid >> 6;
    WqT[e*64 + d] = (_Float16)Wq[((size_t)(960 + d))*1024 + e];
}

// -------------------- main persistent kernel --------------------
// 64 WGs x 256 threads. grp = wgid>>5 (16 batches), cg = wgid&31 (16 cols).
// Phase 0: bwd 16 steps; phase 1: fwd 512 steps. Ring+flags sync.

__global__ __launch_bounds__(256, 1)
void bilstm_main(const float* __restrict__ xg,
                 const float* __restrict__ b_f, const float* __restrict__ b_b,
                 const float* __restrict__ bq,  const float* __restrict__ bk,
                 char* __restrict__ ws, float* __restrict__ out)
{
    extern __shared__ char smem[];
    _Float16* panel = (_Float16*)smem;                              // [16][776]
    float* gates = (float*)(smem + LDS_PANEL_B);                    // [64][68]
    _Float16* hout = (_Float16*)(smem + LDS_PANEL_B + LDS_GATES_B); // [16][16]

    const int tid  = threadIdx.x;
    const int wgid = blockIdx.x;
    const int wave = tid >> 6;
    const int lane = tid & 63;
    const int quad = lane >> 4;
    const int l16  = lane & 15;
    const int grp  = wgid >> 5;            // batch group (16 batches)
    const int cg   = wgid & 31;
    const int col0 = cg * 16;

    unsigned* cnts  = (unsigned*)(ws + OFF_CNT);
    float*   logits = (float*)(ws + OFF_LOGIT);
    float*   hist   = (float*)(ws + OFF_HIST);

    const int ac = tid & 15;     // activation col
    const int ab = tid >> 4;     // activation batch (0..15)

    for (int phase = 0; phase < 2; ++phase) {
        const int dir    = (phase == 0) ? 1 : 0;    // bwd first
        const int nsteps = dir ? 16 : 512;
        _Float16* ring = (_Float16*)(ws + (dir ? OFF_RINGB : OFF_RINGF));
        unsigned* flg  = (unsigned*)(ws + (dir ? OFF_FLAGB : OFF_FLAGF));
        const _Float16* whh = (const _Float16*)(ws + (dir ? OFF_WHHB : OFF_WHHF));
        const _Float16* wih = (const _Float16*)(ws + (dir ? OFF_WIHB : OFF_WIHF));
        const float* bias = dir ? b_b : b_f;
        const int histoff = dir ? 512 : 0;

        // persistent B fragments: rows (gate nt, col l16) x K=768, wave = K-quarter
        v8h bfrag[4][6];
#pragma unroll
        for (int nt = 0; nt < 4; ++nt)
#pragma unroll
            for (int kk = 0; kk < 6; ++kk) {
                const int kb = (wave*6 + kk)*32 + quad*8;
                const int r  = nt*512 + col0 + l16;
                const _Float16* src = (kb < 512) ? (whh + (size_t)r*512 + kb)
                                                 : (wih + (size_t)r*256 + (kb - 512));
                bfrag[nt][kk] = *(const v8h*)src;
            }
        float bia[4];
#pragma unroll
        for (int g = 0; g < 4; ++g) bia[g] = bias[g*512 + col0 + ac];

        float cst = 0.f;

        for (int t = 0; t < nsteps; ++t) {
            const int s = dir ? (511 - t) : t;

            // prefetch x[16 batches][s][:] (1024 float4, 4 per thread)
            float4 xv[4];
#pragma unroll
            for (int i = 0; i < 4; ++i) {
                const int ch = tid + 256*i;
                const int b = ch >> 6, ic = ch & 63;
                xv[i] = *(const float4*)(xg + ((size_t)(grp*16 + b)*512 + s)*256 + ic*4);
            }

            // h_{t-1}: t==0 -> zeros; else poll flag pair + gather ring slot
            if (t == 0) {
                u64* dst = (u64*)(panel + ab*PSTR + ac*32);
#pragma unroll
                for (int j = 0; j < 8; ++j) dst[j] = 0ull;
            } else {
                // this thread's 64B segment = cols [ac*32, ac*32+32) f16
                // -> producers cg = ac*2, ac*2+1 -> flag u64 pair index ac
                const u64* f64 = (const u64*)flg + ((size_t)(t-1)*2 + grp)*16 + ac;
                while (AT_LD(f64) != FLAG_PAIR) {}
                const u64* src = (const u64*)ring
                    + ((((size_t)((t-1) & 3))*2 + grp)*16 + ab)*128 + ac*8;
                u64 w[8];
#pragma unroll
                for (int j = 0; j < 8; ++j) w[j] = AT_LD(src + j);
                u64* dst = (u64*)(panel + ab*PSTR + ac*32);
#pragma unroll
                for (int j = 0; j < 8; ++j) dst[j] = w[j];
            }
            // x (f32 regs -> f16) into panel cols [512,768)
#pragma unroll
            for (int i = 0; i < 4; ++i) {
                const int ch = tid + 256*i;
                const int b = ch >> 6, ic = ch & 63;
                v4h hx = { (_Float16)xv[i].x, (_Float16)xv[i].y,
                           (_Float16)xv[i].z, (_Float16)xv[i].w };
                *(v4h*)(panel + b*PSTR + 512 + ic*4) = hx;
            }
            __syncthreads();   // S_a: panel ready

            // GEMM: gates[b(16)][n(64)] = A[b][768] * W[n][768], K 4-way by wave
            v4f acc[4];
#pragma unroll
            for (int nt = 0; nt < 4; ++nt) { v4f z = {0.f,0.f,0.f,0.f}; acc[nt] = z; }
#pragma unroll
            for (int kk = 0; kk < 6; ++kk) {
                const int kb = (wave*6 + kk)*32 + quad*8;
                const v8h a0 = *(const v8h*)(panel + l16*PSTR + kb);
#pragma unroll
                for (int nt = 0; nt < 4; ++nt)
                    acc[nt] = __builtin_amdgcn_mfma_f32_16x16x32_f16(a0, bfrag[nt][kk], acc[nt], 0, 0, 0);
            }
            // K-partials: gates[n][m(batch)][wave]
#pragma unroll
            for (int nt = 0; nt < 4; ++nt)
#pragma unroll
                for (int r = 0; r < 4; ++r)
                    gates[(nt*16 + l16)*GSTR + (quad*4 + r)*4 + wave] = acc[nt][r];
            __syncthreads();   // S_c: partials ready

            // activations: all 256 threads, one (b=ab, c=ac) each
            {
                float g[4];
#pragma unroll
                for (int gi = 0; gi < 4; ++gi) {
                    const v4f v = *(const v4f*)(gates + (gi*16 + ac)*GSTR + ab*4);
                    g[gi] = v.x + v.y + v.z + v.w + bia[gi];
                }
                const float ig = 1.f/(1.f + __expf(-g[0]));
                const float fg = 1.f/(1.f + __expf(-g[1]));
                const float gg = 1.f - 2.f/(__expf(2.f*g[2]) + 1.f);
                const float og = 1.f/(1.f + __expf(-g[3]));
                cst = fg*cst + ig*gg;
                const float hn = og * (1.f - 2.f/(__expf(2.f*cst) + 1.f));
                hout[ab*16 + ac] = (_Float16)hn;
                if (s >= 496)
                    AT_ST(hist + ((size_t)(grp*16 + ab)*16 + (s - 496))*1024
                               + histoff + col0 + ac, hn);
            }
            __syncthreads();   // S_d: hout ready

            // publish: wave 0 stores 512B data, drains, sets flag
            if (wave == 0) {
                const int b = lane >> 2, seg = lane & 3;
                const u64 v = *(const u64*)(hout + b*16 + seg*4);
                AT_ST((u64*)(ring + ((((size_t)(t & 3))*2 + grp)*16 + b)*512
                             + col0 + seg*4), v);
                asm volatile("s_waitcnt vmcnt(0)" ::: "memory");
                if (lane == 0)
                    AT_ST(flg + ((size_t)t*2 + grp)*32 + cg, 1u);
            }
        }
    }

    // join before epilogue (syncthreads drains hist stores per-wave)
    __syncthreads();
    if (tid == 0) {
        __hip_atomic_fetch_add(cnts + 0, 1u, __ATOMIC_RELAXED, __HIP_MEMORY_SCOPE_AGENT);
        while (AT_LD(cnts + 0) < 64u) {}
    }
    __syncthreads();

    // ---------------- collapsed attention epilogue ----------------
    // 8 pairs per WG: p = wgid*8+pp -> (b = p>>4, r = p&15, s' = 496+r)
    float*    hv  = (float*)smem;                 // [8][1024]
    _Float16* k16 = (_Float16*)(smem + 32768);    // [8][1024]
    float*    qb  = (float*)(smem + 49152);       // [8][64]
    float*    vzb = (float*)(smem + 51200);       // [8][16]
    float*    scb = (float*)(smem + 51712);       // [8][16]
    int*      lastf = (int*)(smem + 53248);

    const _Float16* WkT = (const _Float16*)(ws + OFF_WKT);
    const _Float16* WqT = (const _Float16*)(ws + OFF_WQT);
    const float* wv2 = (const float*)(ws + OFF_WV2);
    const float* cv  = (const float*)(ws + OFF_CV);
    const float* beff= (const float*)(ws + OFF_BEFF);

    const int p0 = wgid * 8;
    {
        const u64* hist64 = (const u64*)hist;
#pragma unroll
        for (int i = 0; i < 16; ++i) {
            const int ch = tid + 256*i;            // 4096 u64 chunks
            const int pp = ch >> 9, e2 = ch & 511;
            const int p = p0 + pp; const int b = p >> 4, r = p & 15;
            const u64 w = AT_LD(hist64 + ((size_t)b*16 + r)*512 + e2);
            *(u64*)(hv + pp*1024 + e2*2) = w;
        }
    }
    __syncthreads();

    // K projection: k[pp][j], j = jj*256+tid
    float kacc[4][8];
#pragma unroll
    for (int jj = 0; jj < 4; ++jj) {
        const float bkv = bk[jj*256 + tid];
#pragma unroll
        for (int pp = 0; pp < 8; ++pp) kacc[jj][pp] = bkv;
    }
    for (int e = 0; e < 1024; ++e) {
        float hvv[8];
#pragma unroll
        for (int pp = 0; pp < 8; ++pp) hvv[pp] = hv[pp*1024 + e];
#pragma unroll
        for (int jj = 0; jj < 4; ++jj) {
            const float w = (float)WkT[(size_t)e*1024 + jj*256 + tid];
#pragma unroll
            for (int pp = 0; pp < 8; ++pp) kacc[jj][pp] += w * hvv[pp];
        }
    }
#pragma unroll
    for (int jj = 0; jj < 4; ++jj)
#pragma unroll
        for (int pp = 0; pp < 8; ++pp)
            k16[pp*1024 + jj*256 + tid] = (_Float16)kacc[jj][pp];

    // Q head 15
    {
        const int d = tid & 63, ph = tid >> 6;
        float a0 = bq[960 + d], a1 = a0;
        for (int e = 0; e < 1024; ++e) {
            const float w = (float)WqT[e*64 + d];
            a0 += w * hv[ph*1024 + e];
            a1 += w * hv[(ph+4)*1024 + e];
        }
        qb[ph*64 + d] = a0;
        qb[(ph+4)*64 + d] = a1;
    }
    // vz[pp][kh]
    if (tid < 128) {
        const int pp = tid >> 4, kh = tid & 15;
        const int r = (p0 + pp) & 15;
        float a = cv[r*16 + kh];
        for (int e = 0; e < 1024; ++e)
            a += wv2[((size_t)r*1024 + e)*16 + kh] * hv[pp*1024 + e];
        vzb[pp*16 + kh] = a;
    }
    __syncthreads();
    if (tid < 128) {
        const int pp = tid >> 4, kh = tid & 15;
        float a = 0.f;
#pragma unroll
        for (int d = 0; d < 64; ++d)
            a += qb[pp*64 + d] * (float)k16[pp*1024 + kh*64 + d];
        scb[pp*16 + kh] = a * 0.125f;
    }
    __syncthreads();
    if (tid < 8) {
        const int base = tid*16;
        float m = scb[base];
        for (int kh = 1; kh < 16; ++kh) m = fmaxf(m, scb[base+kh]);
        float sum = 0.f, wz = 0.f;
        for (int kh = 0; kh < 16; ++kh) {
            const float pe = __expf(scb[base+kh] - m);
            sum += pe; wz += pe * vzb[base+kh];
        }
        atomicAdd(&logits[(p0 + tid) >> 4], wz / sum);
    }
    __syncthreads();
    if (tid == 0) {
        const unsigned old = __hip_atomic_fetch_add(cnts + 1, 1u, __ATOMIC_RELAXED, __HIP_MEMORY_SCOPE_AGENT);
        *lastf = (old == 63u) ? 1 : 0;
    }
    __syncthreads();
    if (*lastf) {
        if (tid < 32) {
            const float lg = AT_LD(logits + tid) + beff[0];
            out[tid] = 1.f/(1.f + __expf(-lg));
        }
    }
}

// -------------------- launcher --------------------

extern "C" void kernel_launch(void* const* d_in, const int* in_sizes, int n_in,
                              void* d_out, int out_size, void* d_ws, size_t ws_size,
                              hipStream_t stream)
{
    (void)in_sizes; (void)n_in; (void)out_size; (void)ws_size;
    const float* x    = (const float*)d_in[0];
    const float* Wihf = (const float*)d_in[1];
    const float* Whhf = (const float*)d_in[2];
    const float* b_f  = (const float*)d_in[3];
    const float* Wihb = (const float*)d_in[4];
    const float* Whhb = (const float*)d_in[5];
    const float* b_b  = (const float*)d_in[6];
    const float* Wq   = (const float*)d_in[7];
    const float* bq   = (const float*)d_in[8];
    const float* Wk   = (const float*)d_in[9];
    const float* bk   = (const float*)d_in[10];
    const float* Wv   = (const float*)d_in[11];
    const float* bv   = (const float*)d_in[12];
    const float* Wo   = (const float*)d_in[13];
    const float* bo   = (const float*)d_in[14];
    const float* Wfc  = (const float*)d_in[15];
    const float* bfc  = (const float*)d_in[16];
    char* ws = (char*)d_ws;
    float* out = (float*)d_out;

    // zero counters/logits/weff/beff + both flag arrays (ring needs no init:
    // reads are gated by flags; hist is fully overwritten)
    hipMemsetAsync(ws, 0, ZERO_BYTES, stream);
    hipLaunchKernelGGL(k_convert, dim3(512), dim3(256), 0, stream, Whhf, Wihf, Whhb, Wihb, ws);
    hipLaunchKernelGGL(k_weff,    dim3(64),  dim3(256), 0, stream, Wfc, Wo, bo, bfc, ws);
    hipLaunchKernelGGL(k_wv2,     dim3(65),  dim3(256), 0, stream, Wv, bv, ws);
    hipLaunchKernelGGL(k_tk,      dim3(1024),dim3(256), 0, stream, Wk, ws);
    hipLaunchKernelGGL(k_tq,      dim3(256), dim3(256), 0, stream, Wq, ws);
    hipLaunchKernelGGL(bilstm_main, dim3(64), dim3(256), DYN_LDS, stream,
                       x, b_f, b_b, bq, bk, ws, out);
}